// Round 1
// baseline (2136.614 us; speedup 1.0000x reference)
//
#include <hip/hip_runtime.h>
#include <math.h>

#define HIDN 1024
#define NHEADS 16
#define HD 64
#define NB 2
#define SL 2048

// ---------------------------------------------------------------------------
// Generic tiled fp32 GEMM with bias: C[M][N] = A[M][K] @ W[K][N] + bias[N]
// 64x64 tile, BK=32, 256 threads, 4x4 per thread.
// ---------------------------------------------------------------------------
__global__ __launch_bounds__(256) void gemm_bias_kernel(
    const float* __restrict__ A, const float* __restrict__ W,
    const float* __restrict__ bias, float* __restrict__ C,
    int M, int N, int K)
{
    __shared__ float As[64][33];
    __shared__ float Ws[32][65];
    const int t = threadIdx.x;
    const int tx = t & 15, ty = t >> 4;
    const int m0 = blockIdx.y * 64, n0 = blockIdx.x * 64;
    float acc[4][4] = {};

    for (int k0 = 0; k0 < K; k0 += 32) {
        #pragma unroll
        for (int i = 0; i < 8; i++) {
            int idx = t + i * 256;
            int m = idx >> 5, kk = idx & 31;
            As[m][kk] = A[(size_t)(m0 + m) * K + k0 + kk];
        }
        #pragma unroll
        for (int i = 0; i < 8; i++) {
            int idx = t + i * 256;
            int kk = idx >> 6, n = idx & 63;
            Ws[kk][n] = W[(size_t)(k0 + kk) * N + n0 + n];
        }
        __syncthreads();
        #pragma unroll
        for (int kk = 0; kk < 32; kk++) {
            float a[4], b[4];
            #pragma unroll
            for (int i = 0; i < 4; i++) a[i] = As[ty * 4 + i][kk];
            #pragma unroll
            for (int j = 0; j < 4; j++) b[j] = Ws[kk][tx * 4 + j];
            #pragma unroll
            for (int i = 0; i < 4; i++)
                #pragma unroll
                for (int j = 0; j < 4; j++) acc[i][j] += a[i] * b[j];
        }
        __syncthreads();
    }
    #pragma unroll
    for (int i = 0; i < 4; i++) {
        int m = m0 + ty * 4 + i;
        #pragma unroll
        for (int j = 0; j < 4; j++) {
            int n = n0 + tx * 4 + j;
            C[(size_t)m * N + n] = acc[i][j] + bias[n];
        }
    }
}

// ---------------------------------------------------------------------------
// Energy: att[b,h,q,k] = (1/8) * dot(Q[b,q,h*64:...], K[b,k,:])
// Per (b,h): M=2048(q) x N=2048(k) x Kd=64.  64x64 tile per block.
// ---------------------------------------------------------------------------
__global__ __launch_bounds__(256) void energy_kernel(
    const float* __restrict__ Q, const float* __restrict__ Km,
    float* __restrict__ att)
{
    __shared__ float Qs[64][65];
    __shared__ float Ks[64][65];
    const int t = threadIdx.x;
    const int k0 = blockIdx.x * 64;
    const int q0 = blockIdx.y * 64;
    const int bh = blockIdx.z;              // b*16 + h
    const int b = bh >> 4, h = bh & 15;

    const float* Qbase = Q + (size_t)b * SL * HIDN + (size_t)h * HD;
    const float* Kbase = Km + (size_t)b * SL * HD;

    #pragma unroll
    for (int i = 0; i < 16; i++) {
        int idx = t + i * 256;
        int r = idx >> 6, d = idx & 63;
        Qs[r][d] = Qbase[(size_t)(q0 + r) * HIDN + d];
        Ks[r][d] = Kbase[(size_t)(k0 + r) * HD + d];
    }
    __syncthreads();

    const int tx = t & 15, ty = t >> 4;
    float acc[4][4] = {};
    #pragma unroll
    for (int d = 0; d < 64; d++) {
        float a[4], bv[4];
        #pragma unroll
        for (int i = 0; i < 4; i++) a[i] = Qs[ty * 4 + i][d];
        #pragma unroll
        for (int j = 0; j < 4; j++) bv[j] = Ks[tx * 4 + j][d];
        #pragma unroll
        for (int i = 0; i < 4; i++)
            #pragma unroll
            for (int j = 0; j < 4; j++) acc[i][j] += a[i] * bv[j];
    }
    float* out = att + ((size_t)bh * SL + q0) * SL + k0;
    #pragma unroll
    for (int i = 0; i < 4; i++)
        #pragma unroll
        for (int j = 0; j < 4; j++)
            out[(size_t)(ty * 4 + i) * SL + tx * 4 + j] = acc[i][j] * 0.125f;
}

// ---------------------------------------------------------------------------
// Row softmax in place: one block (256 thr) per row of 2048.
// ---------------------------------------------------------------------------
__global__ __launch_bounds__(256) void softmax_kernel(float* __restrict__ att)
{
    __shared__ float red[256];
    const int t = threadIdx.x;
    float* p = att + (size_t)blockIdx.x * SL;

    float v[8];
    float mx = -1e30f;
    #pragma unroll
    for (int i = 0; i < 8; i++) {
        v[i] = p[t + i * 256];
        mx = fmaxf(mx, v[i]);
    }
    red[t] = mx;
    __syncthreads();
    for (int s = 128; s > 0; s >>= 1) {
        if (t < s) red[t] = fmaxf(red[t], red[t + s]);
        __syncthreads();
    }
    mx = red[0];
    __syncthreads();

    float sum = 0.f;
    #pragma unroll
    for (int i = 0; i < 8; i++) {
        v[i] = __expf(v[i] - mx);
        sum += v[i];
    }
    red[t] = sum;
    __syncthreads();
    for (int s = 128; s > 0; s >>= 1) {
        if (t < s) red[t] += red[t + s];
        __syncthreads();
    }
    const float inv = 1.f / red[0];
    #pragma unroll
    for (int i = 0; i < 8; i++) p[t + i * 256] = v[i] * inv;
}

// ---------------------------------------------------------------------------
// PV: X[b,q,h*64+d] = sum_k att[b,h,q,k] * V[b,k,d]
// Block = (bh, 16-row q tile); k tiled by 128; 4-way k-slice per thread,
// each thread computes 4q x 4d partials, LDS reduce at the end.
// ---------------------------------------------------------------------------
__global__ __launch_bounds__(256) void pv_kernel(
    const float* __restrict__ att, const float* __restrict__ V,
    float* __restrict__ X)
{
    __shared__ float Ps[16][132];
    __shared__ float Vs[128][64];
    __shared__ float xred[4][16][64];

    const int t = threadIdx.x;
    const int qt = blockIdx.x;              // 0..127
    const int bh = blockIdx.y;              // 0..31
    const int b = bh >> 4, h = bh & 15;
    const int q0 = qt * 16;

    const float* Vbase = V + (size_t)b * SL * HD;
    const float* Abase = att + ((size_t)bh * SL + q0) * SL;

    const int tx = t & 15;          // d group: d = tx*4..tx*4+3
    const int ty = (t >> 4) & 3;    // q group: q = ty*4..ty*4+3
    const int ks = t >> 6;          // k slice 0..3
    float acc[4][4] = {};

    for (int kt = 0; kt < 16; kt++) {
        const int k0 = kt * 128;
        #pragma unroll
        for (int i = 0; i < 8; i++) {
            int idx = t + i * 256;
            int q = idx >> 7, k = idx & 127;
            Ps[q][k] = Abase[(size_t)q * SL + k0 + k];
        }
        #pragma unroll
        for (int i = 0; i < 32; i++) {
            int idx = t + i * 256;
            int k = idx >> 6, d = idx & 63;
            Vs[k][d] = Vbase[(size_t)(k0 + k) * HD + d];
        }
        __syncthreads();
        #pragma unroll
        for (int kk = 0; kk < 32; kk++) {
            int k = ks * 32 + kk;
            float a[4], bv[4];
            #pragma unroll
            for (int i = 0; i < 4; i++) a[i] = Ps[ty * 4 + i][k];
            #pragma unroll
            for (int j = 0; j < 4; j++) bv[j] = Vs[k][tx * 4 + j];
            #pragma unroll
            for (int i = 0; i < 4; i++)
                #pragma unroll
                for (int j = 0; j < 4; j++) acc[i][j] += a[i] * bv[j];
        }
        __syncthreads();
    }

    #pragma unroll
    for (int i = 0; i < 4; i++)
        #pragma unroll
        for (int j = 0; j < 4; j++)
            xred[ks][ty * 4 + i][tx * 4 + j] = acc[i][j];
    __syncthreads();

    #pragma unroll
    for (int i = 0; i < 4; i++) {
        int idx = t + i * 256;
        int q = idx >> 6, d = idx & 63;
        float s = xred[0][q][d] + xred[1][q][d] + xred[2][q][d] + xred[3][q][d];
        X[((size_t)b * SL + q0 + q) * HIDN + (size_t)h * HD + d] = s;
    }
}

// ---------------------------------------------------------------------------
extern "C" void kernel_launch(void* const* d_in, const int* in_sizes, int n_in,
                              void* d_out, int out_size, void* d_ws, size_t ws_size,
                              hipStream_t stream)
{
    const float* query = (const float*)d_in[0];
    const float* key   = (const float*)d_in[1];
    const float* value = (const float*)d_in[2];
    const float* Wq = (const float*)d_in[3];
    const float* bq = (const float*)d_in[4];
    const float* Wk = (const float*)d_in[5];
    const float* bk = (const float*)d_in[6];
    const float* Wv = (const float*)d_in[7];
    const float* bv = (const float*)d_in[8];
    const float* Wo = (const float*)d_in[9];
    const float* bo = (const float*)d_in[10];

    float* out = (float*)d_out;                               // [B, L, HID]
    float* att = (float*)d_out + (size_t)NB * SL * HIDN;      // [B, H, L, L]

    float* ws = (float*)d_ws;
    float* Qw = ws;                                   // 4096 x 1024
    float* Kw = Qw + (size_t)NB * SL * HIDN;          // 4096 x 64
    float* Vw = Kw + (size_t)NB * SL * HD;            // 4096 x 64
    float* Xw = Vw + (size_t)NB * SL * HD;            // 4096 x 1024

    const int M = NB * SL;   // 4096

    // Projections
    gemm_bias_kernel<<<dim3(HIDN / 64, M / 64), 256, 0, stream>>>(
        query, Wq, bq, Qw, M, HIDN, HIDN);
    gemm_bias_kernel<<<dim3(HD / 64, M / 64), 256, 0, stream>>>(
        key, Wk, bk, Kw, M, HD, HIDN);
    gemm_bias_kernel<<<dim3(HD / 64, M / 64), 256, 0, stream>>>(
        value, Wv, bv, Vw, M, HD, HIDN);

    // Energy (raw scores -> attention region)
    energy_kernel<<<dim3(SL / 64, SL / 64, NB * NHEADS), 256, 0, stream>>>(
        Qw, Kw, att);

    // Softmax rows in place
    softmax_kernel<<<dim3(NB * NHEADS * SL), 256, 0, stream>>>(att);

    // PV
    pv_kernel<<<dim3(SL / 16, NB * NHEADS), 256, 0, stream>>>(att, Vw, Xw);

    // Output projection
    gemm_bias_kernel<<<dim3(HIDN / 64, M / 64), 256, 0, stream>>>(
        Xw, Wo, bo, out, M, HIDN, HIDN);
}